// Round 1
// baseline (921.054 us; speedup 1.0000x reference)
//
#include <hip/hip_runtime.h>

// ---------------------------------------------------------------------------
// QGroupLinear: y[m,n] = sum_k x[m,k] * (qw[n,k] * sw[n, k/G]) + bias[n]
// M=4096 (B*S), K=4096, N=11008, G=128.
// Strategy: dequantize qw->bf16 and cast x->bf16 into d_ws, then run an
// m97-style 128x128 bf16 MFMA GEMM (16x16x32), global_load_lds width-16
// staging, 4 waves/block each computing a 64x64 subtile (4x4 frags).
// ---------------------------------------------------------------------------

typedef __attribute__((ext_vector_type(8))) short short8;
typedef __attribute__((ext_vector_type(4))) float floatx4;

__device__ __forceinline__ unsigned short f2bf_rne(float f) {
  union { float f; unsigned int u; } c;
  c.f = f;
  unsigned int u = c.u;
  u += 0x7FFFu + ((u >> 16) & 1u);   // round-to-nearest-even
  return (unsigned short)(u >> 16);
}

// ---- x fp32 -> bf16 (8 elems/thread) --------------------------------------
__global__ void cvt_x_kernel(const float* __restrict__ x,
                             short* __restrict__ xb, long n) {
  long i = ((long)blockIdx.x * blockDim.x + threadIdx.x) * 8;
  if (i >= n) return;
  const float4* p = (const float4*)(x + i);
  float4 a = p[0], b = p[1];
  short8 o;
  o[0] = (short)f2bf_rne(a.x); o[1] = (short)f2bf_rne(a.y);
  o[2] = (short)f2bf_rne(a.z); o[3] = (short)f2bf_rne(a.w);
  o[4] = (short)f2bf_rne(b.x); o[5] = (short)f2bf_rne(b.y);
  o[6] = (short)f2bf_rne(b.z); o[7] = (short)f2bf_rne(b.w);
  *(short8*)(xb + i) = o;
}

// ---- qw int32 * sw -> bf16 (8 elems/thread) -------------------------------
__global__ void dequant_kernel(const int* __restrict__ qw,
                               const float* __restrict__ sw,
                               short* __restrict__ wb,
                               int K, int G, int ngroups) {
  int n = blockIdx.y;
  int kb = (blockIdx.x * blockDim.x + threadIdx.x) * 8;
  if (kb >= K) return;
  const int* q = qw + (long)n * K + kb;
  float s = sw[(long)n * ngroups + kb / G];  // G=128 is a multiple of 8
  int4 q0 = *(const int4*)q;
  int4 q1 = *(const int4*)(q + 4);
  short8 o;
  o[0] = (short)f2bf_rne((float)q0.x * s); o[1] = (short)f2bf_rne((float)q0.y * s);
  o[2] = (short)f2bf_rne((float)q0.z * s); o[3] = (short)f2bf_rne((float)q0.w * s);
  o[4] = (short)f2bf_rne((float)q1.x * s); o[5] = (short)f2bf_rne((float)q1.y * s);
  o[6] = (short)f2bf_rne((float)q1.z * s); o[7] = (short)f2bf_rne((float)q1.w * s);
  *(short8*)(wb + (long)n * K + kb) = o;
}

// ---- bf16 MFMA GEMM: Y[M][N] = Xb[M][K] * Wb[N][K]^T + bias ---------------
#define BM 128
#define BN 128
#define BK 32

__global__ __launch_bounds__(256) void gemm_bt_kernel(
    const short* __restrict__ Xb,    // [M][K] bf16 bits
    const short* __restrict__ Wb,    // [N][K] bf16 bits
    const float* __restrict__ bias,  // [N]
    float* __restrict__ Y,           // [M][N]
    int M, int N, int K) {
  __shared__ short As[BM * BK];  // 8 KB
  __shared__ short Bs[BN * BK];  // 8 KB

  const int t = threadIdx.x;     // 0..255
  const int wave = t >> 6;       // 0..3
  const int lane = t & 63;
  const int wm = wave >> 1;      // 0..1 (m-half)
  const int wn = wave & 1;       // 0..1 (n-half)
  const int quad = lane >> 4;    // 0..3
  const int l16 = lane & 15;

  const int tileM = blockIdx.y * BM;
  const int tileN = blockIdx.x * BN;

  floatx4 acc[4][4];
#pragma unroll
  for (int i = 0; i < 4; i++)
#pragma unroll
    for (int j = 0; j < 4; j++) acc[i][j] = {0.f, 0.f, 0.f, 0.f};

  // staging: thread t loads 16B; tile row = t>>2 (+64), cols (t&3)*8..+8
  const int srow = t >> 2;
  const int scol = (t & 3) * 8;

  const short* Ag = Xb + (long)tileM * K;
  const short* Bg = Wb + (long)tileN * K;

  for (int k0 = 0; k0 < K; k0 += BK) {
#pragma unroll
    for (int i = 0; i < 2; ++i) {
      __builtin_amdgcn_global_load_lds(
          (const __attribute__((address_space(1))) void*)(Ag + (long)(i * 64 + srow) * K + k0 + scol),
          (__attribute__((address_space(3))) void*)(As + i * 64 * BK + t * 8),
          16, 0, 0);
    }
#pragma unroll
    for (int i = 0; i < 2; ++i) {
      __builtin_amdgcn_global_load_lds(
          (const __attribute__((address_space(1))) void*)(Bg + (long)(i * 64 + srow) * K + k0 + scol),
          (__attribute__((address_space(3))) void*)(Bs + i * 64 * BK + t * 8),
          16, 0, 0);
    }
    __syncthreads();  // drains vmcnt (global_load_lds) before use

    const short* Aw = As + wm * 64 * BK;
    const short* Bw = Bs + wn * 64 * BK;
    short8 af[4], bf[4];
#pragma unroll
    for (int i = 0; i < 4; i++)
      af[i] = *(const short8*)(Aw + (i * 16 + l16) * BK + quad * 8);
#pragma unroll
    for (int j = 0; j < 4; j++)
      bf[j] = *(const short8*)(Bw + (j * 16 + l16) * BK + quad * 8);

#pragma unroll
    for (int i = 0; i < 4; i++)
#pragma unroll
      for (int j = 0; j < 4; j++)
        acc[i][j] = __builtin_amdgcn_mfma_f32_16x16x32_bf16(af[i], bf[j],
                                                            acc[i][j], 0, 0, 0);
    __syncthreads();
  }

  // epilogue: C/D layout col=lane&15 (n), row=quad*4+reg (m)
  const int mbase = tileM + wm * 64;
  const int nbase = tileN + wn * 64;
#pragma unroll
  for (int i = 0; i < 4; i++) {
#pragma unroll
    for (int j = 0; j < 4; j++) {
      int n = nbase + j * 16 + l16;
      float bv = bias[n];
#pragma unroll
      for (int r = 0; r < 4; r++) {
        int m = mbase + i * 16 + quad * 4 + r;
        Y[(long)m * N + n] = acc[i][j][r] + bv;
      }
    }
  }
}

// ---- fallback (only if ws too small): correct but slow --------------------
__global__ void naive_kernel(const float* __restrict__ x,
                             const int* __restrict__ qw,
                             const float* __restrict__ sw,
                             const float* __restrict__ bias,
                             float* __restrict__ y,
                             int M, int N, int K, int G) {
  long idx = (long)blockIdx.x * blockDim.x + threadIdx.x;
  if (idx >= (long)M * N) return;
  int m = (int)(idx / N), n = (int)(idx % N);
  int ng = K / G;
  float acc = 0.f;
  for (int g = 0; g < ng; g++) {
    float s = sw[(long)n * ng + g];
    float part = 0.f;
    for (int k = g * G; k < (g + 1) * G; k++)
      part += x[(long)m * K + k] * (float)qw[(long)n * K + k];
    acc += part * s;
  }
  y[idx] = acc + bias[n];
}

extern "C" void kernel_launch(void* const* d_in, const int* in_sizes, int n_in,
                              void* d_out, int out_size, void* d_ws, size_t ws_size,
                              hipStream_t stream) {
  const float* x = (const float*)d_in[0];
  const int* qw = (const int*)d_in[1];
  const float* sw = (const float*)d_in[2];
  const float* bias = (const float*)d_in[3];
  float* y = (float*)d_out;

  const int N = in_sizes[3];
  const int K = in_sizes[1] / N;
  const int M = in_sizes[0] / K;
  const int ngroups = in_sizes[2] / N;
  const int G = K / ngroups;

  const long MK = (long)M * K;
  const long NK = (long)N * K;
  const size_t need = (size_t)(MK + NK) * sizeof(short);

  if (ws_size < need || (M % BM) || (N % BN) || (K % BK) || (G % 8)) {
    long total = (long)M * N;
    naive_kernel<<<(unsigned)((total + 255) / 256), 256, 0, stream>>>(
        x, qw, sw, bias, y, M, N, K, G);
    return;
  }

  short* xb = (short*)d_ws;
  short* wb = xb + MK;

  cvt_x_kernel<<<(unsigned)(MK / 8 / 256), 256, 0, stream>>>(x, xb, MK);
  dim3 dq_grid((unsigned)((K / 8 + 255) / 256), (unsigned)N);
  dequant_kernel<<<dq_grid, 256, 0, stream>>>(qw, sw, wb, K, G, ngroups);

  dim3 grid((unsigned)(N / BN), (unsigned)(M / BM));
  gemm_bt_kernel<<<grid, 256, 0, stream>>>(xb, wb, bias, y, M, N, K);
}

// Round 2
// 824.868 us; speedup vs baseline: 1.1166x; 1.1166x over previous
//
#include <hip/hip_runtime.h>

// ---------------------------------------------------------------------------
// QGroupLinear: y[m,n] = sum_k x[m,k] * (qw[n,k] * sw[n, k/G]) + bias[n]
// M=4096 (B*S), K=4096, N=11008, G=128.
// R2: XOR-swizzled LDS layout to kill the 8-way ds_read_b128 bank conflict
// (R1: SQ_LDS_BANK_CONFLICT=4.5e7, cost model matched 626us dur), plus an
// 8-row grid swizzle for L2 tile reuse.
// ---------------------------------------------------------------------------

typedef __attribute__((ext_vector_type(8))) short short8;
typedef __attribute__((ext_vector_type(4))) float floatx4;

__device__ __forceinline__ unsigned short f2bf_rne(float f) {
  union { float f; unsigned int u; } c;
  c.f = f;
  unsigned int u = c.u;
  u += 0x7FFFu + ((u >> 16) & 1u);   // round-to-nearest-even
  return (unsigned short)(u >> 16);
}

// ---- x fp32 -> bf16 (8 elems/thread) --------------------------------------
__global__ void cvt_x_kernel(const float* __restrict__ x,
                             short* __restrict__ xb, long n) {
  long i = ((long)blockIdx.x * blockDim.x + threadIdx.x) * 8;
  if (i >= n) return;
  const float4* p = (const float4*)(x + i);
  float4 a = p[0], b = p[1];
  short8 o;
  o[0] = (short)f2bf_rne(a.x); o[1] = (short)f2bf_rne(a.y);
  o[2] = (short)f2bf_rne(a.z); o[3] = (short)f2bf_rne(a.w);
  o[4] = (short)f2bf_rne(b.x); o[5] = (short)f2bf_rne(b.y);
  o[6] = (short)f2bf_rne(b.z); o[7] = (short)f2bf_rne(b.w);
  *(short8*)(xb + i) = o;
}

// ---- qw int32 * sw -> bf16 (8 elems/thread) -------------------------------
__global__ void dequant_kernel(const int* __restrict__ qw,
                               const float* __restrict__ sw,
                               short* __restrict__ wb,
                               int K, int G, int ngroups) {
  int n = blockIdx.y;
  int kb = (blockIdx.x * blockDim.x + threadIdx.x) * 8;
  if (kb >= K) return;
  const int* q = qw + (long)n * K + kb;
  float s = sw[(long)n * ngroups + kb / G];  // G=128 is a multiple of 8
  int4 q0 = *(const int4*)q;
  int4 q1 = *(const int4*)(q + 4);
  short8 o;
  o[0] = (short)f2bf_rne((float)q0.x * s); o[1] = (short)f2bf_rne((float)q0.y * s);
  o[2] = (short)f2bf_rne((float)q0.z * s); o[3] = (short)f2bf_rne((float)q0.w * s);
  o[4] = (short)f2bf_rne((float)q1.x * s); o[5] = (short)f2bf_rne((float)q1.y * s);
  o[6] = (short)f2bf_rne((float)q1.z * s); o[7] = (short)f2bf_rne((float)q1.w * s);
  *(short8*)(wb + (long)n * K + kb) = o;
}

// ---- bf16 MFMA GEMM: Y[M][N] = Xb[M][K] * Wb[N][K]^T + bias ---------------
#define BM 128
#define BN 128
#define BK 32

// LDS layout: tile rows of BK=32 shorts (4 chunks of 16B). Physical chunk
// (r, cc) holds GLOBAL chunk (r, cc ^ ((r>>1)&3)). With this, a fragment
// read (16 lanes, fixed quad) covers all 8 bank-line positions 2x each ->
// 2-way, free (m136). Staging writes are forced linear by global_load_lds;
// we permute the *fetched* global chunk instead (same 64B row segment, so
// coalescing is unchanged).

__global__ __launch_bounds__(256) void gemm_bt_kernel(
    const short* __restrict__ Xb,    // [M][K] bf16 bits
    const short* __restrict__ Wb,    // [N][K] bf16 bits
    const float* __restrict__ bias,  // [N]
    float* __restrict__ Y,           // [M][N]
    int M, int N, int K) {
  __shared__ short As[BM * BK];  // 8 KB
  __shared__ short Bs[BN * BK];  // 8 KB

  const int t = threadIdx.x;     // 0..255
  const int wave = t >> 6;       // 0..3
  const int lane = t & 63;
  const int wm = wave >> 1;      // 0..1 (m-half)
  const int wn = wave & 1;       // 0..1 (n-half)
  const int quad = lane >> 4;    // 0..3
  const int l16 = lane & 15;

  // ---- grid swizzle: groups of 8 M-tiles, sweep N within group ----
  const int gridN = gridDim.x, gridM = gridDim.y;
  int tileMi, tileNi;
  if ((gridM & 7) == 0) {
    int bid = blockIdx.y * gridN + blockIdx.x;
    int gsz = gridN << 3;                // 8 * gridN
    int group = bid / gsz;
    int rem = bid - group * gsz;
    tileMi = (group << 3) + (rem & 7);
    tileNi = rem >> 3;
  } else {
    tileMi = blockIdx.y; tileNi = blockIdx.x;
  }
  const int tileM = tileMi * BM;
  const int tileN = tileNi * BN;

  floatx4 acc[4][4];
#pragma unroll
  for (int i = 0; i < 4; i++)
#pragma unroll
    for (int j = 0; j < 4; j++) acc[i][j] = {0.f, 0.f, 0.f, 0.f};

  // staging: thread t fills physical chunk t (16B at As + t*8 shorts).
  // It must fetch GLOBAL chunk (row = t>>2, col = (t&3) ^ ((t>>3)&3)).
  const int srow = t >> 2;
  const int scol = ((t & 3) ^ ((t >> 3) & 3)) * 8;   // shorts

  const short* Ag = Xb + (long)tileM * K;
  const short* Bg = Wb + (long)tileN * K;

  // fragment read: global chunk q of row r lives at physical chunk
  // q ^ ((r>>1)&3); with r = i*16+l16 this reduces to q ^ ((l16>>1)&3).
  const int cswz = (quad ^ ((l16 >> 1) & 3)) * 8;    // shorts

  for (int k0 = 0; k0 < K; k0 += BK) {
#pragma unroll
    for (int i = 0; i < 2; ++i) {
      __builtin_amdgcn_global_load_lds(
          (const __attribute__((address_space(1))) void*)(Ag + (long)(i * 64 + srow) * K + k0 + scol),
          (__attribute__((address_space(3))) void*)(As + i * 64 * BK + t * 8),
          16, 0, 0);
    }
#pragma unroll
    for (int i = 0; i < 2; ++i) {
      __builtin_amdgcn_global_load_lds(
          (const __attribute__((address_space(1))) void*)(Bg + (long)(i * 64 + srow) * K + k0 + scol),
          (__attribute__((address_space(3))) void*)(Bs + i * 64 * BK + t * 8),
          16, 0, 0);
    }
    __syncthreads();  // drains vmcnt (global_load_lds) before use

    const short* Aw = As + wm * 64 * BK;
    const short* Bw = Bs + wn * 64 * BK;
    short8 af[4], bf[4];
#pragma unroll
    for (int i = 0; i < 4; i++)
      af[i] = *(const short8*)(Aw + (i * 16 + l16) * BK + cswz);
#pragma unroll
    for (int j = 0; j < 4; j++)
      bf[j] = *(const short8*)(Bw + (j * 16 + l16) * BK + cswz);

#pragma unroll
    for (int i = 0; i < 4; i++)
#pragma unroll
      for (int j = 0; j < 4; j++)
        acc[i][j] = __builtin_amdgcn_mfma_f32_16x16x32_bf16(af[i], bf[j],
                                                            acc[i][j], 0, 0, 0);
    __syncthreads();
  }

  // epilogue: C/D layout col=lane&15 (n), row=quad*4+reg (m)
  const int mbase = tileM + wm * 64;
  const int nbase = tileN + wn * 64;
#pragma unroll
  for (int i = 0; i < 4; i++) {
#pragma unroll
    for (int j = 0; j < 4; j++) {
      int n = nbase + j * 16 + l16;
      float bv = bias[n];
#pragma unroll
      for (int r = 0; r < 4; r++) {
        int m = mbase + i * 16 + quad * 4 + r;
        Y[(long)m * N + n] = acc[i][j][r] + bv;
      }
    }
  }
}

// ---- fallback (only if ws too small): correct but slow --------------------
__global__ void naive_kernel(const float* __restrict__ x,
                             const int* __restrict__ qw,
                             const float* __restrict__ sw,
                             const float* __restrict__ bias,
                             float* __restrict__ y,
                             int M, int N, int K, int G) {
  long idx = (long)blockIdx.x * blockDim.x + threadIdx.x;
  if (idx >= (long)M * N) return;
  int m = (int)(idx / N), n = (int)(idx % N);
  int ng = K / G;
  float acc = 0.f;
  for (int g = 0; g < ng; g++) {
    float s = sw[(long)n * ng + g];
    float part = 0.f;
    for (int k = g * G; k < (g + 1) * G; k++)
      part += x[(long)m * K + k] * (float)qw[(long)n * K + k];
    acc += part * s;
  }
  y[idx] = acc + bias[n];
}

extern "C" void kernel_launch(void* const* d_in, const int* in_sizes, int n_in,
                              void* d_out, int out_size, void* d_ws, size_t ws_size,
                              hipStream_t stream) {
  const float* x = (const float*)d_in[0];
  const int* qw = (const int*)d_in[1];
  const float* sw = (const float*)d_in[2];
  const float* bias = (const float*)d_in[3];
  float* y = (float*)d_out;

  const int N = in_sizes[3];
  const int K = in_sizes[1] / N;
  const int M = in_sizes[0] / K;
  const int ngroups = in_sizes[2] / N;
  const int G = K / ngroups;

  const long MK = (long)M * K;
  const long NK = (long)N * K;
  const size_t need = (size_t)(MK + NK) * sizeof(short);

  if (ws_size < need || (M % BM) || (N % BN) || (K % BK) || (G % 8)) {
    long total = (long)M * N;
    naive_kernel<<<(unsigned)((total + 255) / 256), 256, 0, stream>>>(
        x, qw, sw, bias, y, M, N, K, G);
    return;
  }

  short* xb = (short*)d_ws;
  short* wb = xb + MK;

  cvt_x_kernel<<<(unsigned)(MK / 8 / 256), 256, 0, stream>>>(x, xb, MK);
  dim3 dq_grid((unsigned)((K / 8 + 255) / 256), (unsigned)N);
  dequant_kernel<<<dq_grid, 256, 0, stream>>>(qw, sw, wb, K, G, ngroups);

  dim3 grid((unsigned)(N / BN), (unsigned)(M / BM));
  gemm_bt_kernel<<<grid, 256, 0, stream>>>(xb, wb, bias, y, M, N, K);
}

// Round 3
// 736.374 us; speedup vs baseline: 1.2508x; 1.1202x over previous
//
#include <hip/hip_runtime.h>

// ---------------------------------------------------------------------------
// QGroupLinear: y[m,n] = sum_k x[m,k] * (qw[n,k] * sw[n, k/G]) + bias[n]
// M=4096 (B*S), K=4096, N=11008, G=128.
// R3: (a) __launch_bounds__(256,4) to fit 128 unified regs -> 4 blocks/CU
//     (R2 was 80 VGPR + 64 AGPR = 144 -> 3 waves/SIMD, Occupancy 31%);
//     (b) XCD-aware swizzle: each XCD owns a 4-M-tile stripe and sweeps N,
//     so a B panel is reused 4x inside one XCD's L2 (R2 map spread the 8
//     sharers across 8 XCDs -> FETCH 1.5 GB);
//     (c) preprocess merged into one grid-stride kernel.
// R2 carry: XOR-swizzled LDS (SQ_LDS_BANK_CONFLICT 4.5e7 -> 0).
// ---------------------------------------------------------------------------

typedef __attribute__((ext_vector_type(8))) short short8;
typedef __attribute__((ext_vector_type(4))) float floatx4;

__device__ __forceinline__ unsigned short f2bf_rne(float f) {
  union { float f; unsigned int u; } c;
  c.f = f;
  unsigned int u = c.u;
  u += 0x7FFFu + ((u >> 16) & 1u);   // round-to-nearest-even
  return (unsigned short)(u >> 16);
}

// ---- merged preprocess: xb = bf16(x); wb = bf16(qw * sw) ------------------
// One chunk = 8 output elements. Chunks [0, MK/8) are cvt, rest are dequant.
__global__ void prep_kernel(const float* __restrict__ x,
                            const int* __restrict__ qw,
                            const float* __restrict__ sw,
                            short* __restrict__ xb,
                            short* __restrict__ wb,
                            long nx_chunks, long total_chunks,
                            int K, int G, int ngroups) {
  long stride = (long)gridDim.x * blockDim.x;
  for (long c = (long)blockIdx.x * blockDim.x + threadIdx.x;
       c < total_chunks; c += stride) {
    if (c < nx_chunks) {
      long i = c * 8;
      const float4* p = (const float4*)(x + i);
      float4 a = p[0], b = p[1];
      short8 o;
      o[0] = (short)f2bf_rne(a.x); o[1] = (short)f2bf_rne(a.y);
      o[2] = (short)f2bf_rne(a.z); o[3] = (short)f2bf_rne(a.w);
      o[4] = (short)f2bf_rne(b.x); o[5] = (short)f2bf_rne(b.y);
      o[6] = (short)f2bf_rne(b.z); o[7] = (short)f2bf_rne(b.w);
      *(short8*)(xb + i) = o;
    } else {
      long e = (c - nx_chunks) * 8;
      int n = (int)(e / K);
      int k = (int)(e - (long)n * K);
      const int* q = qw + (long)n * K + k;
      float s = sw[(long)n * ngroups + k / G];  // G % 8 == 0 guaranteed by caller
      int4 q0 = *(const int4*)q;
      int4 q1 = *(const int4*)(q + 4);
      short8 o;
      o[0] = (short)f2bf_rne((float)q0.x * s);
      o[1] = (short)f2bf_rne((float)q0.y * s);
      o[2] = (short)f2bf_rne((float)q0.z * s);
      o[3] = (short)f2bf_rne((float)q0.w * s);
      o[4] = (short)f2bf_rne((float)q1.x * s);
      o[5] = (short)f2bf_rne((float)q1.y * s);
      o[6] = (short)f2bf_rne((float)q1.z * s);
      o[7] = (short)f2bf_rne((float)q1.w * s);
      *(short8*)(wb + e) = o;
    }
  }
}

// ---- bf16 MFMA GEMM: Y[M][N] = Xb[M][K] * Wb[N][K]^T + bias ---------------
#define BM 128
#define BN 128
#define BK 32

// LDS layout: tile rows of BK=32 shorts (4 chunks of 16B). Physical chunk
// (r, cc) holds GLOBAL chunk (r, cc ^ ((r>>1)&3)) -> fragment reads are
// 2-way (free) instead of 8-way. Staging fetches the permuted global chunk
// (same 64B row segment, coalescing unchanged).

__global__ __launch_bounds__(256, 4) void gemm_bt_kernel(
    const short* __restrict__ Xb,    // [M][K] bf16 bits
    const short* __restrict__ Wb,    // [N][K] bf16 bits
    const float* __restrict__ bias,  // [N]
    float* __restrict__ Y,           // [M][N]
    int M, int N, int K) {
  __shared__ short As[BM * BK];  // 8 KB
  __shared__ short Bs[BN * BK];  // 8 KB

  const int t = threadIdx.x;     // 0..255
  const int wave = t >> 6;       // 0..3
  const int lane = t & 63;
  const int wm = wave >> 1;      // 0..1 (m-half)
  const int wn = wave & 1;       // 0..1 (n-half)
  const int quad = lane >> 4;    // 0..3
  const int l16 = lane & 15;

  // ---- XCD-aware swizzle: xcd = bid%8 owns M-tile stripe [xcd*S, xcd*S+S),
  // sweeps N; 4 consecutive same-XCD blocks share one B panel in that L2.
  const int gn = gridDim.x, gm = gridDim.y;
  int mt, nt;
  if ((gm & 7) == 0) {
    int stripe = gm >> 3;
    int bid = blockIdx.y * gn + blockIdx.x;
    int xcd = bid & 7;
    int q = bid >> 3;
    int msub = q % stripe;
    nt = q / stripe;
    mt = xcd * stripe + msub;
  } else {
    mt = blockIdx.y; nt = blockIdx.x;
  }
  const int tileM = mt * BM;
  const int tileN = nt * BN;

  floatx4 acc[4][4];
#pragma unroll
  for (int i = 0; i < 4; i++)
#pragma unroll
    for (int j = 0; j < 4; j++) acc[i][j] = {0.f, 0.f, 0.f, 0.f};

  // staging: thread t fills physical chunk t (16B at As + t*8 shorts);
  // fetches GLOBAL chunk (row = t>>2, col = (t&3) ^ ((t>>3)&3)).
  const int srow = t >> 2;
  const int scol = ((t & 3) ^ ((t >> 3) & 3)) * 8;   // shorts

  const short* Ag = Xb + (long)tileM * K;
  const short* Bg = Wb + (long)tileN * K;

  // fragment read: global chunk q of row r is at physical chunk
  // q ^ ((r>>1)&3); r = i*16+l16 -> q ^ ((l16>>1)&3).
  const int cswz = (quad ^ ((l16 >> 1) & 3)) * 8;    // shorts

  for (int k0 = 0; k0 < K; k0 += BK) {
#pragma unroll
    for (int i = 0; i < 2; ++i) {
      __builtin_amdgcn_global_load_lds(
          (const __attribute__((address_space(1))) void*)(Ag + (long)(i * 64 + srow) * K + k0 + scol),
          (__attribute__((address_space(3))) void*)(As + i * 64 * BK + t * 8),
          16, 0, 0);
    }
#pragma unroll
    for (int i = 0; i < 2; ++i) {
      __builtin_amdgcn_global_load_lds(
          (const __attribute__((address_space(1))) void*)(Bg + (long)(i * 64 + srow) * K + k0 + scol),
          (__attribute__((address_space(3))) void*)(Bs + i * 64 * BK + t * 8),
          16, 0, 0);
    }
    __syncthreads();  // drains vmcnt (global_load_lds) before use

    const short* Aw = As + wm * 64 * BK;
    const short* Bw = Bs + wn * 64 * BK;
    short8 af[4], bf[4];
#pragma unroll
    for (int i = 0; i < 4; i++)
      af[i] = *(const short8*)(Aw + (i * 16 + l16) * BK + cswz);
#pragma unroll
    for (int j = 0; j < 4; j++)
      bf[j] = *(const short8*)(Bw + (j * 16 + l16) * BK + cswz);

#pragma unroll
    for (int i = 0; i < 4; i++)
#pragma unroll
      for (int j = 0; j < 4; j++)
        acc[i][j] = __builtin_amdgcn_mfma_f32_16x16x32_bf16(af[i], bf[j],
                                                            acc[i][j], 0, 0, 0);
    __syncthreads();
  }

  // epilogue: C/D layout col=lane&15 (n), row=quad*4+reg (m)
  const int mbase = tileM + wm * 64;
  const int nbase = tileN + wn * 64;
#pragma unroll
  for (int i = 0; i < 4; i++) {
#pragma unroll
    for (int j = 0; j < 4; j++) {
      int n = nbase + j * 16 + l16;
      float bv = bias[n];
#pragma unroll
      for (int r = 0; r < 4; r++) {
        int m = mbase + i * 16 + quad * 4 + r;
        Y[(long)m * N + n] = acc[i][j][r] + bv;
      }
    }
  }
}

// ---- fallback (only if ws too small / odd shapes): correct but slow -------
__global__ void naive_kernel(const float* __restrict__ x,
                             const int* __restrict__ qw,
                             const float* __restrict__ sw,
                             const float* __restrict__ bias,
                             float* __restrict__ y,
                             int M, int N, int K, int G) {
  long idx = (long)blockIdx.x * blockDim.x + threadIdx.x;
  if (idx >= (long)M * N) return;
  int m = (int)(idx / N), n = (int)(idx % N);
  int ng = K / G;
  float acc = 0.f;
  for (int g = 0; g < ng; g++) {
    float s = sw[(long)n * ng + g];
    float part = 0.f;
    for (int k = g * G; k < (g + 1) * G; k++)
      part += x[(long)m * K + k] * (float)qw[(long)n * K + k];
    acc += part * s;
  }
  y[idx] = acc + bias[n];
}

extern "C" void kernel_launch(void* const* d_in, const int* in_sizes, int n_in,
                              void* d_out, int out_size, void* d_ws, size_t ws_size,
                              hipStream_t stream) {
  const float* x = (const float*)d_in[0];
  const int* qw = (const int*)d_in[1];
  const float* sw = (const float*)d_in[2];
  const float* bias = (const float*)d_in[3];
  float* y = (float*)d_out;

  const int N = in_sizes[3];
  const int K = in_sizes[1] / N;
  const int M = in_sizes[0] / K;
  const int ngroups = in_sizes[2] / N;
  const int G = K / ngroups;

  const long MK = (long)M * K;
  const long NK = (long)N * K;
  const size_t need = (size_t)(MK + NK) * sizeof(short);

  if (ws_size < need || (M % BM) || (N % BN) || (K % BK) || (G % 8)) {
    long total = (long)M * N;
    naive_kernel<<<(unsigned)((total + 255) / 256), 256, 0, stream>>>(
        x, qw, sw, bias, y, M, N, K, G);
    return;
  }

  short* xb = (short*)d_ws;
  short* wb = xb + MK;

  long nx_chunks = MK / 8;
  long total_chunks = nx_chunks + NK / 8;
  // 2048 blocks (8/CU), grid-stride
  prep_kernel<<<2048, 256, 0, stream>>>(x, qw, sw, xb, wb,
                                        nx_chunks, total_chunks, K, G, ngroups);

  dim3 grid((unsigned)(N / BN), (unsigned)(M / BM));
  gemm_bt_kernel<<<grid, 256, 0, stream>>>(xb, wb, bias, y, M, N, K);
}